// Round 1
// baseline (780.925 us; speedup 1.0000x reference)
//
#include <hip/hip_runtime.h>

#define NN 50000
#define D 128

// ---------------- CSR build ----------------

__global__ void hist_k(const int* __restrict__ ei, int E, int* __restrict__ count) {
    int e = blockIdx.x * 256 + threadIdx.x;
    if (e < E) atomicAdd(&count[ei[E + e]], 1);
}

__global__ void chunk_sum_k(const int* __restrict__ count, int n, int* __restrict__ partial) {
    int i = blockIdx.x * 256 + threadIdx.x;
    int v = (i < n) ? count[i] : 0;
    for (int off = 32; off; off >>= 1) v += __shfl_down(v, off);
    __shared__ int ws[4];
    int lane = threadIdx.x & 63, wave = threadIdx.x >> 6;
    if (lane == 0) ws[wave] = v;
    __syncthreads();
    if (threadIdx.x == 0) partial[blockIdx.x] = ws[0] + ws[1] + ws[2] + ws[3];
}

__global__ void scan_serial_k(int* partial, int nchunk) {
    if (threadIdx.x == 0 && blockIdx.x == 0) {
        int run = 0;
        for (int i = 0; i < nchunk; ++i) { int t = partial[i]; partial[i] = run; run += t; }
    }
}

__global__ void rowptr_k(const int* __restrict__ count, const int* __restrict__ partial,
                         int n, int* __restrict__ rowptr) {
    int i = blockIdx.x * 256 + threadIdx.x;
    int c = (i < n) ? count[i] : 0;
    int lane = threadIdx.x & 63, wave = threadIdx.x >> 6;
    int incl = c;
    for (int off = 1; off < 64; off <<= 1) {
        int nv = __shfl_up(incl, off);
        if (lane >= off) incl += nv;
    }
    __shared__ int ws[4];
    if (lane == 63) ws[wave] = incl;
    __syncthreads();
    int base = 0;
    for (int w = 0; w < 3; ++w) if (w < wave) base += ws[w];
    if (i < n) rowptr[i] = partial[blockIdx.x] + base + incl - c;
}

__global__ void fill_k(const int* __restrict__ ei, int E,
                       const int* __restrict__ rowptr, int* __restrict__ cur,
                       int* __restrict__ csr) {
    int e = blockIdx.x * 256 + threadIdx.x;
    if (e < E) {
        int d = ei[E + e];
        int pos = rowptr[d] + atomicAdd(&cur[d], 1);
        csr[pos] = ei[e];
    }
}

// ---------------- mean aggregation (gather over CSR) ----------------
// block = 256 threads = 2 nodes x 128 features

__global__ void agg_k(const float* __restrict__ x,
                      const int* __restrict__ count, const int* __restrict__ rowptr,
                      const int* __restrict__ csr, float* __restrict__ agg) {
    int t = threadIdx.x;
    int n = blockIdx.x * 2 + (t >> 7);
    int f = t & 127;
    int deg = count[n];
    int ro  = rowptr[n];
    float s = 0.f;
    for (int i = 0; i < deg; ++i) {
        int sidx = csr[ro + i];
        s += x[(size_t)sidx * D + f];
    }
    float inv = (deg > 0) ? (1.f / (float)deg) : 0.f;
    agg[(size_t)n * D + f] = s * inv;
}

// ---------------- transform: out = relu?(agg@Wl^T + x@Wr^T + bl) ----------------
// 256 threads: thread handles output feature j = t&127 for 4 nodes (half = t>>7
// picks which 4 of the tile's 8). Weights in 128 KiB dynamic LDS, XOR-swizzled
// float4 layout so wave-wide ds_read_b128 at fixed column spreads over all banks.

__global__ __launch_bounds__(256) void transform_k(
    const float* __restrict__ agg, const float* __restrict__ xin,
    const float* __restrict__ Wl, const float* __restrict__ Wr,
    const float* __restrict__ bl, float* __restrict__ out,
    int ntiles, int relu) {
    extern __shared__ float4 sm[];
    float4* sWl = sm;          // [128][32] float4, swizzled
    float4* sWr = sm + 4096;
    int t = threadIdx.x;
    for (int it = 0; it < 16; ++it) {
        int idx = it * 256 + t;        // 0..4095
        int j = idx >> 5, c = idx & 31;
        int cs = c ^ (j & 7);
        sWl[j * 32 + cs] = ((const float4*)Wl)[idx];
        sWr[j * 32 + cs] = ((const float4*)Wr)[idx];
    }
    __syncthreads();

    int j    = t & 127;
    int half = t >> 7;
    int jx   = j & 7;
    float b  = bl[j];

    for (int tile = blockIdx.x; tile < ntiles; tile += gridDim.x) {
        int nbase = tile * 8 + half * 4;
        const float4* a0 = (const float4*)(agg + (size_t)nbase * D);
        const float4* x0 = (const float4*)(xin + (size_t)nbase * D);
        float acc0 = b, acc1 = b, acc2 = b, acc3 = b;
        #pragma unroll 4
        for (int c = 0; c < 32; ++c) {
            float4 wl = sWl[j * 32 + (c ^ jx)];
            float4 wr = sWr[j * 32 + (c ^ jx)];
            float4 a, xx;
            a = a0[c];        xx = x0[c];
            acc0 += wl.x*a.x + wl.y*a.y + wl.z*a.z + wl.w*a.w
                  + wr.x*xx.x + wr.y*xx.y + wr.z*xx.z + wr.w*xx.w;
            a = a0[32 + c];   xx = x0[32 + c];
            acc1 += wl.x*a.x + wl.y*a.y + wl.z*a.z + wl.w*a.w
                  + wr.x*xx.x + wr.y*xx.y + wr.z*xx.z + wr.w*xx.w;
            a = a0[64 + c];   xx = x0[64 + c];
            acc2 += wl.x*a.x + wl.y*a.y + wl.z*a.z + wl.w*a.w
                  + wr.x*xx.x + wr.y*xx.y + wr.z*xx.z + wr.w*xx.w;
            a = a0[96 + c];   xx = x0[96 + c];
            acc3 += wl.x*a.x + wl.y*a.y + wl.z*a.z + wl.w*a.w
                  + wr.x*xx.x + wr.y*xx.y + wr.z*xx.z + wr.w*xx.w;
        }
        if (relu) {
            acc0 = fmaxf(acc0, 0.f); acc1 = fmaxf(acc1, 0.f);
            acc2 = fmaxf(acc2, 0.f); acc3 = fmaxf(acc3, 0.f);
        }
        float* op = out + (size_t)nbase * D + j;
        op[0]     = acc0;
        op[D]     = acc1;
        op[2 * D] = acc2;
        op[3 * D] = acc3;
    }
}

extern "C" void kernel_launch(void* const* d_in, const int* in_sizes, int n_in,
                              void* d_out, int out_size, void* d_ws, size_t ws_size,
                              hipStream_t stream) {
    const float* x  = (const float*)d_in[0];
    const int*   ei = (const int*)d_in[1];
    const float* Wl = (const float*)d_in[2];
    const float* bl = (const float*)d_in[3];
    const float* Wr = (const float*)d_in[4];
    float* out = (float*)d_out;

    const int N = NN;
    const int E = in_sizes[1] / 2;

    // ws layout (int units): count[N] | cur[N] | rowptr[N] | partial[256] | csr[E] | agg | h
    int* ws      = (int*)d_ws;
    int* count   = ws;
    int* cur     = ws + N;
    int* rowptr  = ws + 2 * N;
    int* partial = ws + 3 * N;
    int* csr     = ws + 3 * N + 256;
    size_t aggOff = ((size_t)(3 * N + 256 + E) + 3) & ~(size_t)3;
    float* agg = (float*)d_ws + aggOff;
    float* h   = agg + (size_t)N * D;

    (void)hipFuncSetAttribute((const void*)transform_k,
                              hipFuncAttributeMaxDynamicSharedMemorySize, 131072);

    hipMemsetAsync(count, 0, (size_t)2 * N * sizeof(int), stream);  // count + cur

    int eb = (E + 255) / 256;
    int nchunk = (N + 255) / 256;
    hist_k<<<eb, 256, 0, stream>>>(ei, E, count);
    chunk_sum_k<<<nchunk, 256, 0, stream>>>(count, N, partial);
    scan_serial_k<<<1, 64, 0, stream>>>(partial, nchunk);
    rowptr_k<<<nchunk, 256, 0, stream>>>(count, partial, N, rowptr);
    fill_k<<<eb, 256, 0, stream>>>(ei, E, rowptr, cur, csr);

    // layer 1
    agg_k<<<N / 2, 256, 0, stream>>>(x, count, rowptr, csr, agg);
    transform_k<<<256, 256, 131072, stream>>>(agg, x, Wl, Wr, bl, h, N / 8, 1);
    // layer 2
    agg_k<<<N / 2, 256, 0, stream>>>(h, count, rowptr, csr, agg);
    transform_k<<<256, 256, 131072, stream>>>(agg, h, Wl, Wr, bl, out, N / 8, 0);
}

// Round 2
// 647.131 us; speedup vs baseline: 1.2067x; 1.2067x over previous
//
#include <hip/hip_runtime.h>

#define NN 50000
#define D 128

// ---------------- CSR build ----------------

__global__ void hist_k(const int* __restrict__ ei, int E, int* __restrict__ count) {
    int e = blockIdx.x * 256 + threadIdx.x;
    if (e < E) atomicAdd(&count[ei[E + e]], 1);
}

__global__ void chunk_sum_k(const int* __restrict__ count, int n, int* __restrict__ partial) {
    int i = blockIdx.x * 256 + threadIdx.x;
    int v = (i < n) ? count[i] : 0;
    for (int off = 32; off; off >>= 1) v += __shfl_down(v, off);
    __shared__ int ws[4];
    int lane = threadIdx.x & 63, wave = threadIdx.x >> 6;
    if (lane == 0) ws[wave] = v;
    __syncthreads();
    if (threadIdx.x == 0) partial[blockIdx.x] = ws[0] + ws[1] + ws[2] + ws[3];
}

__global__ void scan_serial_k(int* partial, int nchunk) {
    if (threadIdx.x == 0 && blockIdx.x == 0) {
        int run = 0;
        for (int i = 0; i < nchunk; ++i) { int t = partial[i]; partial[i] = run; run += t; }
    }
}

__global__ void rowptr_k(const int* __restrict__ count, const int* __restrict__ partial,
                         int n, int* __restrict__ rowptr) {
    int i = blockIdx.x * 256 + threadIdx.x;
    int c = (i < n) ? count[i] : 0;
    int lane = threadIdx.x & 63, wave = threadIdx.x >> 6;
    int incl = c;
    for (int off = 1; off < 64; off <<= 1) {
        int nv = __shfl_up(incl, off);
        if (lane >= off) incl += nv;
    }
    __shared__ int ws[4];
    if (lane == 63) ws[wave] = incl;
    __syncthreads();
    int base = 0;
    for (int w = 0; w < 3; ++w) if (w < wave) base += ws[w];
    if (i < n) rowptr[i] = partial[blockIdx.x] + base + incl - c;
}

__global__ void fill_k(const int* __restrict__ ei, int E,
                       const int* __restrict__ rowptr, int* __restrict__ cur,
                       int* __restrict__ csr) {
    int e = blockIdx.x * 256 + threadIdx.x;
    if (e < E) {
        int d = ei[E + e];
        int pos = rowptr[d] + atomicAdd(&cur[d], 1);
        csr[pos] = ei[e];
    }
}

// ---------------- mean aggregation (gather over CSR) ----------------
// 256 threads = 8 nodes x 32 float4-columns; 2-way neighbor unroll

__global__ void agg_k(const float* __restrict__ x,
                      const int* __restrict__ count, const int* __restrict__ rowptr,
                      const int* __restrict__ csr, float* __restrict__ agg) {
    int t = threadIdx.x;
    int n = blockIdx.x * 8 + (t >> 5);
    int c = t & 31;
    int deg = count[n];
    int ro  = rowptr[n];
    const float4* x4 = (const float4*)x;
    float sx = 0.f, sy = 0.f, sz = 0.f, sw = 0.f;
    int i = 0;
    for (; i + 2 <= deg; i += 2) {
        int s0 = csr[ro + i], s1 = csr[ro + i + 1];
        float4 v0 = x4[(size_t)s0 * 32 + c];
        float4 v1 = x4[(size_t)s1 * 32 + c];
        sx += v0.x + v1.x; sy += v0.y + v1.y;
        sz += v0.z + v1.z; sw += v0.w + v1.w;
    }
    if (i < deg) {
        int s0 = csr[ro + i];
        float4 v0 = x4[(size_t)s0 * 32 + c];
        sx += v0.x; sy += v0.y; sz += v0.z; sw += v0.w;
    }
    float inv = (deg > 0) ? (1.f / (float)deg) : 0.f;
    float4 r; r.x = sx * inv; r.y = sy * inv; r.z = sz * inv; r.w = sw * inv;
    ((float4*)agg)[(size_t)n * 32 + c] = r;
}

// ---------------- transform: out = relu?(agg@Wl^T + x@Wr^T + bl) ----------------
// 1024 threads (4 waves/SIMD with 128 KiB LDS, 1 block/CU): thread owns output
// feature j = t&127 for 4 nodes; q = t>>7 picks which 4 of the tile's 32 nodes.
// Weights in 128 KiB dynamic LDS, XOR-swizzled float4 layout (c ^ (j&7)) so a
// wave-wide ds_read_b128 at fixed c spreads over all 32 banks.

__global__ __launch_bounds__(1024) void transform_k(
    const float* __restrict__ agg, const float* __restrict__ xin,
    const float* __restrict__ Wl, const float* __restrict__ Wr,
    const float* __restrict__ bl, float* __restrict__ out,
    int ntiles, int N, int relu) {
    extern __shared__ float4 sm[];
    float4* sWl = sm;          // [128][32] float4, swizzled
    float4* sWr = sm + 4096;
    int t = threadIdx.x;
    for (int it = 0; it < 4; ++it) {
        int idx = it * 1024 + t;       // 0..4095
        int j = idx >> 5, c = idx & 31;
        int cs = c ^ (j & 7);
        sWl[j * 32 + cs] = ((const float4*)Wl)[idx];
        sWr[j * 32 + cs] = ((const float4*)Wr)[idx];
    }
    __syncthreads();

    int j    = t & 127;
    int q    = t >> 7;          // 0..7
    int jx   = j & 7;
    float b  = bl[j];

    for (int tile = blockIdx.x; tile < ntiles; tile += gridDim.x) {
        int nbase = tile * 32 + q * 4;
        int r0 = nbase, r1 = nbase + 1, r2 = nbase + 2, r3 = nbase + 3;
        if (r3 >= N) {                       // tail tile: clamp loads
            r0 = min(r0, N - 1); r1 = min(r1, N - 1);
            r2 = min(r2, N - 1); r3 = min(r3, N - 1);
        }
        const float4* A0 = (const float4*)(agg + (size_t)r0 * D);
        const float4* A1 = (const float4*)(agg + (size_t)r1 * D);
        const float4* A2 = (const float4*)(agg + (size_t)r2 * D);
        const float4* A3 = (const float4*)(agg + (size_t)r3 * D);
        const float4* X0 = (const float4*)(xin + (size_t)r0 * D);
        const float4* X1 = (const float4*)(xin + (size_t)r1 * D);
        const float4* X2 = (const float4*)(xin + (size_t)r2 * D);
        const float4* X3 = (const float4*)(xin + (size_t)r3 * D);
        float acc0 = b, acc1 = b, acc2 = b, acc3 = b;
        #pragma unroll 4
        for (int c = 0; c < 32; ++c) {
            float4 wl = sWl[j * 32 + (c ^ jx)];
            float4 wr = sWr[j * 32 + (c ^ jx)];
            float4 a, xx;
            a = A0[c]; xx = X0[c];
            acc0 += wl.x*a.x + wl.y*a.y + wl.z*a.z + wl.w*a.w
                  + wr.x*xx.x + wr.y*xx.y + wr.z*xx.z + wr.w*xx.w;
            a = A1[c]; xx = X1[c];
            acc1 += wl.x*a.x + wl.y*a.y + wl.z*a.z + wl.w*a.w
                  + wr.x*xx.x + wr.y*xx.y + wr.z*xx.z + wr.w*xx.w;
            a = A2[c]; xx = X2[c];
            acc2 += wl.x*a.x + wl.y*a.y + wl.z*a.z + wl.w*a.w
                  + wr.x*xx.x + wr.y*xx.y + wr.z*xx.z + wr.w*xx.w;
            a = A3[c]; xx = X3[c];
            acc3 += wl.x*a.x + wl.y*a.y + wl.z*a.z + wl.w*a.w
                  + wr.x*xx.x + wr.y*xx.y + wr.z*xx.z + wr.w*xx.w;
        }
        if (relu) {
            acc0 = fmaxf(acc0, 0.f); acc1 = fmaxf(acc1, 0.f);
            acc2 = fmaxf(acc2, 0.f); acc3 = fmaxf(acc3, 0.f);
        }
        float* op = out + (size_t)nbase * D + j;
        if (nbase < N)     op[0]     = acc0;
        if (nbase + 1 < N) op[D]     = acc1;
        if (nbase + 2 < N) op[2 * D] = acc2;
        if (nbase + 3 < N) op[3 * D] = acc3;
    }
}

extern "C" void kernel_launch(void* const* d_in, const int* in_sizes, int n_in,
                              void* d_out, int out_size, void* d_ws, size_t ws_size,
                              hipStream_t stream) {
    const float* x  = (const float*)d_in[0];
    const int*   ei = (const int*)d_in[1];
    const float* Wl = (const float*)d_in[2];
    const float* bl = (const float*)d_in[3];
    const float* Wr = (const float*)d_in[4];
    float* out = (float*)d_out;

    const int N = NN;
    const int E = in_sizes[1] / 2;
    const int NPAD = 50016;            // N rounded up to 32 (tile size)

    // ws layout (int units): count[N] | cur[N] | rowptr[N] | partial[256] | csr[E] | agg | h
    int* ws      = (int*)d_ws;
    int* count   = ws;
    int* cur     = ws + N;
    int* rowptr  = ws + 2 * N;
    int* partial = ws + 3 * N;
    int* csr     = ws + 3 * N + 256;
    size_t aggOff = ((size_t)(3 * N + 256 + E) + 3) & ~(size_t)3;
    float* agg = (float*)d_ws + aggOff;
    float* h   = agg + (size_t)NPAD * D;

    (void)hipFuncSetAttribute((const void*)transform_k,
                              hipFuncAttributeMaxDynamicSharedMemorySize, 131072);

    hipMemsetAsync(count, 0, (size_t)2 * N * sizeof(int), stream);  // count + cur

    int eb = (E + 255) / 256;
    int nchunk = (N + 255) / 256;
    hist_k<<<eb, 256, 0, stream>>>(ei, E, count);
    chunk_sum_k<<<nchunk, 256, 0, stream>>>(count, N, partial);
    scan_serial_k<<<1, 64, 0, stream>>>(partial, nchunk);
    rowptr_k<<<nchunk, 256, 0, stream>>>(count, partial, N, rowptr);
    fill_k<<<eb, 256, 0, stream>>>(ei, E, rowptr, cur, csr);

    int ntiles = (N + 31) / 32;        // 1563
    // layer 1
    agg_k<<<(N + 7) / 8, 256, 0, stream>>>(x, count, rowptr, csr, agg);
    transform_k<<<ntiles, 1024, 131072, stream>>>(agg, x, Wl, Wr, bl, h, ntiles, N, 1);
    // layer 2
    agg_k<<<(N + 7) / 8, 256, 0, stream>>>(h, count, rowptr, csr, agg);
    transform_k<<<ntiles, 1024, 131072, stream>>>(agg, h, Wl, Wr, bl, out, ntiles, N, 0);
}

// Round 3
// 306.636 us; speedup vs baseline: 2.5467x; 2.1104x over previous
//
#include <hip/hip_runtime.h>

#define NN 50000
#define D 128

// ---------------- CSR build ----------------

__global__ void hist_k(const int* __restrict__ ei, int E, int* __restrict__ count) {
    int e = blockIdx.x * 256 + threadIdx.x;
    if (e < E) atomicAdd(&count[ei[E + e]], 1);
}

__global__ void chunk_sum_k(const int* __restrict__ count, int n, int* __restrict__ partial) {
    int i = blockIdx.x * 256 + threadIdx.x;
    int v = (i < n) ? count[i] : 0;
    for (int off = 32; off; off >>= 1) v += __shfl_down(v, off);
    __shared__ int ws[4];
    int lane = threadIdx.x & 63, wave = threadIdx.x >> 6;
    if (lane == 0) ws[wave] = v;
    __syncthreads();
    if (threadIdx.x == 0) partial[blockIdx.x] = ws[0] + ws[1] + ws[2] + ws[3];
}

__global__ void scan_serial_k(int* partial, int nchunk) {
    if (threadIdx.x == 0 && blockIdx.x == 0) {
        int run = 0;
        for (int i = 0; i < nchunk; ++i) { int t = partial[i]; partial[i] = run; run += t; }
    }
}

__global__ void rowptr_k(const int* __restrict__ count, const int* __restrict__ partial,
                         int n, int* __restrict__ rowptr) {
    int i = blockIdx.x * 256 + threadIdx.x;
    int c = (i < n) ? count[i] : 0;
    int lane = threadIdx.x & 63, wave = threadIdx.x >> 6;
    int incl = c;
    for (int off = 1; off < 64; off <<= 1) {
        int nv = __shfl_up(incl, off);
        if (lane >= off) incl += nv;
    }
    __shared__ int ws[4];
    if (lane == 63) ws[wave] = incl;
    __syncthreads();
    int base = 0;
    for (int w = 0; w < 3; ++w) if (w < wave) base += ws[w];
    if (i < n) rowptr[i] = partial[blockIdx.x] + base + incl - c;
}

__global__ void fill_k(const int* __restrict__ ei, int E,
                       const int* __restrict__ rowptr, int* __restrict__ cur,
                       int* __restrict__ csr) {
    int e = blockIdx.x * 256 + threadIdx.x;
    if (e < E) {
        int d = ei[E + e];
        int pos = rowptr[d] + atomicAdd(&cur[d], 1);
        csr[pos] = ei[e];
    }
}

// ---------------- weight pre-transpose: wt[k][n] = (k<128?Wl:Wr)[n][k&127] ----

__global__ void wt_k(const float* __restrict__ Wl, const float* __restrict__ Wr,
                     float* __restrict__ wt) {
    int k = blockIdx.x;        // 0..255
    int n = threadIdx.x;       // 0..127
    const float* W = (k < 128) ? Wl : Wr;
    wt[k * 128 + n] = W[n * 128 + (k & 127)];
}

// ---------------- mean aggregation (gather over CSR) ----------------
// 256 threads = 8 nodes x 32 float4-columns; 2-way neighbor unroll

__global__ void agg_k(const float* __restrict__ x,
                      const int* __restrict__ count, const int* __restrict__ rowptr,
                      const int* __restrict__ csr, float* __restrict__ agg) {
    int t = threadIdx.x;
    int n = blockIdx.x * 8 + (t >> 5);
    int c = t & 31;
    int deg = count[n];
    int ro  = rowptr[n];
    const float4* x4 = (const float4*)x;
    float sx = 0.f, sy = 0.f, sz = 0.f, sw = 0.f;
    int i = 0;
    for (; i + 2 <= deg; i += 2) {
        int s0 = csr[ro + i], s1 = csr[ro + i + 1];
        float4 v0 = x4[(size_t)s0 * 32 + c];
        float4 v1 = x4[(size_t)s1 * 32 + c];
        sx += v0.x + v1.x; sy += v0.y + v1.y;
        sz += v0.z + v1.z; sw += v0.w + v1.w;
    }
    if (i < deg) {
        int s0 = csr[ro + i];
        float4 v0 = x4[(size_t)s0 * 32 + c];
        sx += v0.x; sy += v0.y; sz += v0.z; sw += v0.w;
    }
    float inv = (deg > 0) ? (1.f / (float)deg) : 0.f;
    float4 r; r.x = sx * inv; r.y = sy * inv; r.z = sz * inv; r.w = sw * inv;
    ((float4*)agg)[(size_t)n * 32 + c] = r;
}

// ---------------- transform as register-tiled GEMM ----------------
// out[M=50000,128] = relu?( [agg|x] @ wt + b ), K=256 in 8 chunks of 32.
// Block 256 thr = 64-node x 128-feature tile; thread = 4 nodes x 8 features.
// A-tile transposed into LDS (coalesced global loads, lane-spread);
// W chunk straight-copied from pre-transposed wt.

__global__ __launch_bounds__(256) void transform_k(
    const float* __restrict__ agg, const float* __restrict__ xin,
    const float* __restrict__ wt, const float* __restrict__ bl,
    float* __restrict__ out, int N, int relu) {
    __shared__ float At[32][68];    // [k][m], pad 68: 16B-aligned rows, low conflicts
    __shared__ float Ws[32][132];   // [k][n]

    int tid = threadIdx.x;
    int tx = tid & 15;              // feature group: n0 = tx*4, +64
    int ty = tid >> 4;              // node group:    m0 = ty*4
    int tb = blockIdx.x * 64;

    float4 bLo = *(const float4*)(bl + tx * 4);
    float4 bHi = *(const float4*)(bl + tx * 4 + 64);

    float acc[4][8];
    #pragma unroll
    for (int mi = 0; mi < 4; ++mi) {
        acc[mi][0] = bLo.x; acc[mi][1] = bLo.y; acc[mi][2] = bLo.z; acc[mi][3] = bLo.w;
        acc[mi][4] = bHi.x; acc[mi][5] = bHi.y; acc[mi][6] = bHi.z; acc[mi][7] = bHi.w;
    }

    int arow = tid >> 2;            // 0..63 (tile row for A staging)
    int aseg = tid & 3;             // 0..3  (8 k's each)
    int grow = min(tb + arow, N - 1);
    int wlk  = tid >> 3;            // 0..31 (k row for W staging)
    int wn   = (tid & 7) * 16;      // 16 floats

    for (int kc = 0; kc < 8; ++kc) {
        const float* src = (kc < 4) ? agg : xin;
        int col = (kc & 3) * 32 + aseg * 8;
        const float* ap = src + (size_t)grow * D + col;
        float4 v0 = *(const float4*)(ap);
        float4 v1 = *(const float4*)(ap + 4);
        const float* wp = wt + ((size_t)kc * 32 + wlk) * 128 + wn;
        float4 w0 = *(const float4*)(wp);
        float4 w1 = *(const float4*)(wp + 4);
        float4 w2 = *(const float4*)(wp + 8);
        float4 w3 = *(const float4*)(wp + 12);

        int lk = aseg * 8;
        At[lk + 0][arow] = v0.x; At[lk + 1][arow] = v0.y;
        At[lk + 2][arow] = v0.z; At[lk + 3][arow] = v0.w;
        At[lk + 4][arow] = v1.x; At[lk + 5][arow] = v1.y;
        At[lk + 6][arow] = v1.z; At[lk + 7][arow] = v1.w;
        *(float4*)&Ws[wlk][wn]      = w0;
        *(float4*)&Ws[wlk][wn + 4]  = w1;
        *(float4*)&Ws[wlk][wn + 8]  = w2;
        *(float4*)&Ws[wlk][wn + 12] = w3;
        __syncthreads();

        #pragma unroll 4
        for (int k = 0; k < 32; ++k) {
            float4 a4 = *(float4*)&At[k][ty * 4];
            float4 wv0 = *(float4*)&Ws[k][tx * 4];
            float4 wv1 = *(float4*)&Ws[k][tx * 4 + 64];
            float a[4] = {a4.x, a4.y, a4.z, a4.w};
            float w[8] = {wv0.x, wv0.y, wv0.z, wv0.w, wv1.x, wv1.y, wv1.z, wv1.w};
            #pragma unroll
            for (int mi = 0; mi < 4; ++mi)
                #pragma unroll
                for (int j = 0; j < 8; ++j)
                    acc[mi][j] += a[mi] * w[j];
        }
        __syncthreads();
    }

    #pragma unroll
    for (int mi = 0; mi < 4; ++mi) {
        int gm = tb + ty * 4 + mi;
        if (gm < N) {
            float4 o0, o1;
            o0.x = acc[mi][0]; o0.y = acc[mi][1]; o0.z = acc[mi][2]; o0.w = acc[mi][3];
            o1.x = acc[mi][4]; o1.y = acc[mi][5]; o1.z = acc[mi][6]; o1.w = acc[mi][7];
            if (relu) {
                o0.x = fmaxf(o0.x, 0.f); o0.y = fmaxf(o0.y, 0.f);
                o0.z = fmaxf(o0.z, 0.f); o0.w = fmaxf(o0.w, 0.f);
                o1.x = fmaxf(o1.x, 0.f); o1.y = fmaxf(o1.y, 0.f);
                o1.z = fmaxf(o1.z, 0.f); o1.w = fmaxf(o1.w, 0.f);
            }
            float* op = out + (size_t)gm * D + tx * 4;
            *(float4*)(op)      = o0;
            *(float4*)(op + 64) = o1;
        }
    }
}

extern "C" void kernel_launch(void* const* d_in, const int* in_sizes, int n_in,
                              void* d_out, int out_size, void* d_ws, size_t ws_size,
                              hipStream_t stream) {
    const float* x  = (const float*)d_in[0];
    const int*   ei = (const int*)d_in[1];
    const float* Wl = (const float*)d_in[2];
    const float* bl = (const float*)d_in[3];
    const float* Wr = (const float*)d_in[4];
    float* out = (float*)d_out;

    const int N = NN;
    const int E = in_sizes[1] / 2;
    const int NPAD = 50016;

    // ws layout (int units): count[N] | cur[N] | rowptr[N] | partial[256] | csr[E]
    //                        | wt[256*128 f] | agg | h
    int* ws      = (int*)d_ws;
    int* count   = ws;
    int* cur     = ws + N;
    int* rowptr  = ws + 2 * N;
    int* partial = ws + 3 * N;
    int* csr     = ws + 3 * N + 256;
    size_t wtOff = ((size_t)(3 * N + 256 + E) + 3) & ~(size_t)3;
    float* wt  = (float*)d_ws + wtOff;
    float* agg = wt + 256 * 128;
    float* h   = agg + (size_t)NPAD * D;

    hipMemsetAsync(count, 0, (size_t)2 * N * sizeof(int), stream);  // count + cur

    int eb = (E + 255) / 256;
    int nchunk = (N + 255) / 256;
    hist_k<<<eb, 256, 0, stream>>>(ei, E, count);
    chunk_sum_k<<<nchunk, 256, 0, stream>>>(count, N, partial);
    scan_serial_k<<<1, 64, 0, stream>>>(partial, nchunk);
    rowptr_k<<<nchunk, 256, 0, stream>>>(count, partial, N, rowptr);
    fill_k<<<eb, 256, 0, stream>>>(ei, E, rowptr, cur, csr);
    wt_k<<<256, 128, 0, stream>>>(Wl, Wr, wt);

    int tblocks = (N + 63) / 64;       // 782
    // layer 1
    agg_k<<<(N + 7) / 8, 256, 0, stream>>>(x, count, rowptr, csr, agg);
    transform_k<<<tblocks, 256, 0, stream>>>(agg, x, wt, bl, h, N, 1);
    // layer 2
    agg_k<<<(N + 7) / 8, 256, 0, stream>>>(h, count, rowptr, csr, agg);
    transform_k<<<tblocks, 256, 0, stream>>>(agg, h, wt, bl, out, N, 0);
}

// Round 4
// 299.029 us; speedup vs baseline: 2.6115x; 1.0254x over previous
//
#include <hip/hip_runtime.h>

#define NN 50000
#define D 128

__device__ __forceinline__ unsigned bf16r(float f) {   // RNE round to bf16 (top 16 bits)
    unsigned u = __float_as_uint(f);
    return (u + 0x7FFFu + ((u >> 16) & 1u)) >> 16;
}

// ---------------- CSR build ----------------

__global__ void hist_k(const int* __restrict__ ei, int E, int* __restrict__ count) {
    int e = blockIdx.x * 256 + threadIdx.x;
    if (e < E) atomicAdd(&count[ei[E + e]], 1);
}

__global__ void chunk_sum_k(const int* __restrict__ count, int n, int* __restrict__ partial) {
    int i = blockIdx.x * 256 + threadIdx.x;
    int v = (i < n) ? count[i] : 0;
    for (int off = 32; off; off >>= 1) v += __shfl_down(v, off);
    __shared__ int ws[4];
    int lane = threadIdx.x & 63, wave = threadIdx.x >> 6;
    if (lane == 0) ws[wave] = v;
    __syncthreads();
    if (threadIdx.x == 0) partial[blockIdx.x] = ws[0] + ws[1] + ws[2] + ws[3];
}

__global__ void scan_serial_k(int* partial, int nchunk) {
    if (threadIdx.x == 0 && blockIdx.x == 0) {
        int run = 0;
        for (int i = 0; i < nchunk; ++i) { int t = partial[i]; partial[i] = run; run += t; }
    }
}

__global__ void rowptr_k(const int* __restrict__ count, const int* __restrict__ partial,
                         int n, int* __restrict__ rowptr) {
    int i = blockIdx.x * 256 + threadIdx.x;
    int c = (i < n) ? count[i] : 0;
    int lane = threadIdx.x & 63, wave = threadIdx.x >> 6;
    int incl = c;
    for (int off = 1; off < 64; off <<= 1) {
        int nv = __shfl_up(incl, off);
        if (lane >= off) incl += nv;
    }
    __shared__ int ws[4];
    if (lane == 63) ws[wave] = incl;
    __syncthreads();
    int base = 0;
    for (int w = 0; w < 3; ++w) if (w < wave) base += ws[w];
    if (i < n) rowptr[i] = partial[blockIdx.x] + base + incl - c;
}

__global__ void fill_k(const int* __restrict__ ei, int E,
                       const int* __restrict__ rowptr, int* __restrict__ cur,
                       int* __restrict__ csr) {
    int e = blockIdx.x * 256 + threadIdx.x;
    if (e < E) {
        int d = ei[E + e];
        int pos = rowptr[d] + atomicAdd(&cur[d], 1);
        csr[pos] = ei[e];
    }
}

// ---------------- weight pre-transpose: wt[k][n] = (k<128?Wl:Wr)[n][k&127] ----

__global__ void wt_k(const float* __restrict__ Wl, const float* __restrict__ Wr,
                     float* __restrict__ wt) {
    int k = blockIdx.x;        // 0..255
    int n = threadIdx.x;       // 0..127
    const float* W = (k < 128) ? Wl : Wr;
    wt[k * 128 + n] = W[n * 128 + (k & 127)];
}

// ---------------- f32 -> packed bf16 pairs (u32 = hi<<16 | lo) ----------------
// one thread: float4 -> uint2

__global__ void cvt_k(const float* __restrict__ in, uint* __restrict__ out, int nquad) {
    int i = blockIdx.x * 256 + threadIdx.x;
    if (i >= nquad) return;
    float4 v = ((const float4*)in)[i];
    uint2 p;
    p.x = (bf16r(v.y) << 16) | bf16r(v.x);
    p.y = (bf16r(v.w) << 16) | bf16r(v.z);
    ((uint2*)out)[i] = p;
}

// ---------------- mean aggregation (gather bf16 over CSR) ----------------
// 256 threads = 8 nodes x 32 uint2-columns (8 B/lane, 256 B/row); f32 accum.

__global__ void agg_k(const uint* __restrict__ xb,
                      const int* __restrict__ count, const int* __restrict__ rowptr,
                      const int* __restrict__ csr, float* __restrict__ agg) {
    int t = threadIdx.x;
    int n = blockIdx.x * 8 + (t >> 5);
    int c = t & 31;
    int deg = count[n];
    int ro  = rowptr[n];
    const uint2* x2 = (const uint2*)xb;          // row stride 32 uint2
    float a0 = 0.f, a1 = 0.f, a2 = 0.f, a3 = 0.f;
    int i = 0;
    for (; i + 2 <= deg; i += 2) {
        int s0 = csr[ro + i], s1 = csr[ro + i + 1];
        uint2 u = x2[(size_t)s0 * 32 + c];
        uint2 v = x2[(size_t)s1 * 32 + c];
        a0 += __uint_as_float(u.x << 16)        + __uint_as_float(v.x << 16);
        a1 += __uint_as_float(u.x & 0xFFFF0000u) + __uint_as_float(v.x & 0xFFFF0000u);
        a2 += __uint_as_float(u.y << 16)        + __uint_as_float(v.y << 16);
        a3 += __uint_as_float(u.y & 0xFFFF0000u) + __uint_as_float(v.y & 0xFFFF0000u);
    }
    if (i < deg) {
        int s0 = csr[ro + i];
        uint2 u = x2[(size_t)s0 * 32 + c];
        a0 += __uint_as_float(u.x << 16);
        a1 += __uint_as_float(u.x & 0xFFFF0000u);
        a2 += __uint_as_float(u.y << 16);
        a3 += __uint_as_float(u.y & 0xFFFF0000u);
    }
    float inv = (deg > 0) ? (1.f / (float)deg) : 0.f;
    float4 r; r.x = a0 * inv; r.y = a1 * inv; r.z = a2 * inv; r.w = a3 * inv;
    ((float4*)agg)[(size_t)n * 32 + c] = r;     // floats 4c..4c+3 of row n
}

// ---------------- transform as register-tiled GEMM ----------------
// out[M,128] = relu?( [agg|x] @ wt + b ); optional fused bf16-pack of the
// output into hb (for next layer's gather).

__global__ __launch_bounds__(256) void transform_k(
    const float* __restrict__ agg, const float* __restrict__ xin,
    const float* __restrict__ wt, const float* __restrict__ bl,
    float* __restrict__ out, uint* __restrict__ hb, int N, int relu) {
    __shared__ float At[32][68];
    __shared__ float Ws[32][132];

    int tid = threadIdx.x;
    int tx = tid & 15;
    int ty = tid >> 4;
    int tb = blockIdx.x * 64;

    float4 bLo = *(const float4*)(bl + tx * 4);
    float4 bHi = *(const float4*)(bl + tx * 4 + 64);

    float acc[4][8];
    #pragma unroll
    for (int mi = 0; mi < 4; ++mi) {
        acc[mi][0] = bLo.x; acc[mi][1] = bLo.y; acc[mi][2] = bLo.z; acc[mi][3] = bLo.w;
        acc[mi][4] = bHi.x; acc[mi][5] = bHi.y; acc[mi][6] = bHi.z; acc[mi][7] = bHi.w;
    }

    int arow = tid >> 2;
    int aseg = tid & 3;
    int grow = min(tb + arow, N - 1);
    int wlk  = tid >> 3;
    int wn   = (tid & 7) * 16;

    for (int kc = 0; kc < 8; ++kc) {
        const float* src = (kc < 4) ? agg : xin;
        int col = (kc & 3) * 32 + aseg * 8;
        const float* ap = src + (size_t)grow * D + col;
        float4 v0 = *(const float4*)(ap);
        float4 v1 = *(const float4*)(ap + 4);
        const float* wp = wt + ((size_t)kc * 32 + wlk) * 128 + wn;
        float4 w0 = *(const float4*)(wp);
        float4 w1 = *(const float4*)(wp + 4);
        float4 w2 = *(const float4*)(wp + 8);
        float4 w3 = *(const float4*)(wp + 12);

        int lk = aseg * 8;
        At[lk + 0][arow] = v0.x; At[lk + 1][arow] = v0.y;
        At[lk + 2][arow] = v0.z; At[lk + 3][arow] = v0.w;
        At[lk + 4][arow] = v1.x; At[lk + 5][arow] = v1.y;
        At[lk + 6][arow] = v1.z; At[lk + 7][arow] = v1.w;
        *(float4*)&Ws[wlk][wn]      = w0;
        *(float4*)&Ws[wlk][wn + 4]  = w1;
        *(float4*)&Ws[wlk][wn + 8]  = w2;
        *(float4*)&Ws[wlk][wn + 12] = w3;
        __syncthreads();

        #pragma unroll 4
        for (int k = 0; k < 32; ++k) {
            float4 a4 = *(float4*)&At[k][ty * 4];
            float4 wv0 = *(float4*)&Ws[k][tx * 4];
            float4 wv1 = *(float4*)&Ws[k][tx * 4 + 64];
            float a[4] = {a4.x, a4.y, a4.z, a4.w};
            float w[8] = {wv0.x, wv0.y, wv0.z, wv0.w, wv1.x, wv1.y, wv1.z, wv1.w};
            #pragma unroll
            for (int mi = 0; mi < 4; ++mi)
                #pragma unroll
                for (int j = 0; j < 8; ++j)
                    acc[mi][j] += a[mi] * w[j];
        }
        __syncthreads();
    }

    #pragma unroll
    for (int mi = 0; mi < 4; ++mi) {
        int gm = tb + ty * 4 + mi;
        if (gm < N) {
            float4 o0, o1;
            o0.x = acc[mi][0]; o0.y = acc[mi][1]; o0.z = acc[mi][2]; o0.w = acc[mi][3];
            o1.x = acc[mi][4]; o1.y = acc[mi][5]; o1.z = acc[mi][6]; o1.w = acc[mi][7];
            if (relu) {
                o0.x = fmaxf(o0.x, 0.f); o0.y = fmaxf(o0.y, 0.f);
                o0.z = fmaxf(o0.z, 0.f); o0.w = fmaxf(o0.w, 0.f);
                o1.x = fmaxf(o1.x, 0.f); o1.y = fmaxf(o1.y, 0.f);
                o1.z = fmaxf(o1.z, 0.f); o1.w = fmaxf(o1.w, 0.f);
            }
            float* op = out + (size_t)gm * D + tx * 4;
            *(float4*)(op)      = o0;
            *(float4*)(op + 64) = o1;
            if (hb) {                         // fused bf16 pack for next gather
                uint2 p0, p1;
                p0.x = (bf16r(o0.y) << 16) | bf16r(o0.x);
                p0.y = (bf16r(o0.w) << 16) | bf16r(o0.z);
                p1.x = (bf16r(o1.y) << 16) | bf16r(o1.x);
                p1.y = (bf16r(o1.w) << 16) | bf16r(o1.z);
                uint* hp = hb + (size_t)gm * 64 + tx * 2;
                *(uint2*)(hp)      = p0;
                *(uint2*)(hp + 32) = p1;
            }
        }
    }
}

extern "C" void kernel_launch(void* const* d_in, const int* in_sizes, int n_in,
                              void* d_out, int out_size, void* d_ws, size_t ws_size,
                              hipStream_t stream) {
    const float* x  = (const float*)d_in[0];
    const int*   ei = (const int*)d_in[1];
    const float* Wl = (const float*)d_in[2];
    const float* bl = (const float*)d_in[3];
    const float* Wr = (const float*)d_in[4];
    float* out = (float*)d_out;

    const int N = NN;
    const int E = in_sizes[1] / 2;
    const int NPAD = 50016;

    // ws layout (int units): count[N] | cur[N] | rowptr[N] | partial[256] | csr[E]
    //                        | wt[32768 f] | agg[NPAD*128 f] | h[NPAD*128 f] | xb[N*64 u32]
    int* ws      = (int*)d_ws;
    int* count   = ws;
    int* cur     = ws + N;
    int* rowptr  = ws + 2 * N;
    int* partial = ws + 3 * N;
    int* csr     = ws + 3 * N + 256;
    size_t wtOff = ((size_t)(3 * N + 256 + E) + 3) & ~(size_t)3;
    float* wt  = (float*)d_ws + wtOff;
    float* agg = wt + 256 * 128;
    float* h   = agg + (size_t)NPAD * D;
    uint*  xb  = (uint*)(h + (size_t)NPAD * D);   // reused as hb after layer-1 agg

    hipMemsetAsync(count, 0, (size_t)2 * N * sizeof(int), stream);  // count + cur

    int eb = (E + 255) / 256;
    int nchunk = (N + 255) / 256;
    hist_k<<<eb, 256, 0, stream>>>(ei, E, count);
    chunk_sum_k<<<nchunk, 256, 0, stream>>>(count, N, partial);
    scan_serial_k<<<1, 64, 0, stream>>>(partial, nchunk);
    rowptr_k<<<nchunk, 256, 0, stream>>>(count, partial, N, rowptr);
    fill_k<<<eb, 256, 0, stream>>>(ei, E, rowptr, cur, csr);
    wt_k<<<256, 128, 0, stream>>>(Wl, Wr, wt);
    cvt_k<<<(N * 32 + 255) / 256, 256, 0, stream>>>(x, xb, N * 32);   // N*128/4 quads

    int tblocks = (N + 63) / 64;
    // layer 1 (xb consumed by agg, then reused as hb output of transform)
    agg_k<<<N / 8, 256, 0, stream>>>(xb, count, rowptr, csr, agg);
    transform_k<<<tblocks, 256, 0, stream>>>(agg, x, wt, bl, h, xb, N, 1);
    // layer 2
    agg_k<<<N / 8, 256, 0, stream>>>(xb, count, rowptr, csr, agg);
    transform_k<<<tblocks, 256, 0, stream>>>(agg, h, wt, bl, out, (uint*)nullptr, N, 0);
}

// Round 5
// 202.810 us; speedup vs baseline: 3.8505x; 1.4744x over previous
//
#include <hip/hip_runtime.h>

#define NN 50000
#define D 128

typedef short bf16x8 __attribute__((ext_vector_type(8)));
typedef float f32x16 __attribute__((ext_vector_type(16)));

__device__ __forceinline__ unsigned bf16r(float f) {   // RNE round to bf16
    unsigned u = __float_as_uint(f);
    return (u + 0x7FFFu + ((u >> 16) & 1u)) >> 16;
}
__device__ __forceinline__ float bflo(unsigned u) { return __uint_as_float(u << 16); }
__device__ __forceinline__ float bfhi(unsigned u) { return __uint_as_float(u & 0xFFFF0000u); }

// ---------------- CSR build ----------------

__global__ void hist_k(const int* __restrict__ ei, int E, int* __restrict__ count) {
    int e = blockIdx.x * 256 + threadIdx.x;
    if (e < E) atomicAdd(&count[ei[E + e]], 1);
}

__global__ void chunk_sum_k(const int* __restrict__ count, int n, int* __restrict__ partial) {
    int i = blockIdx.x * 256 + threadIdx.x;
    int v = (i < n) ? count[i] : 0;
    for (int off = 32; off; off >>= 1) v += __shfl_down(v, off);
    __shared__ int ws[4];
    int lane = threadIdx.x & 63, wave = threadIdx.x >> 6;
    if (lane == 0) ws[wave] = v;
    __syncthreads();
    if (threadIdx.x == 0) partial[blockIdx.x] = ws[0] + ws[1] + ws[2] + ws[3];
}

// parallel exclusive scan over <=256 chunk sums (replaces 196-iter serial loop)
__global__ void scan_block_k(int* partial, int nchunk) {
    __shared__ int sm[256];
    int t = threadIdx.x;
    int v = (t < nchunk) ? partial[t] : 0;
    sm[t] = v;
    __syncthreads();
    for (int off = 1; off < 256; off <<= 1) {
        int add = (t >= off) ? sm[t - off] : 0;
        __syncthreads();
        sm[t] += add;
        __syncthreads();
    }
    if (t < nchunk) partial[t] = sm[t] - v;   // exclusive
}

__global__ void rowptr_k(const int* __restrict__ count, const int* __restrict__ partial,
                         int n, int* __restrict__ rowptr) {
    int i = blockIdx.x * 256 + threadIdx.x;
    int c = (i < n) ? count[i] : 0;
    int lane = threadIdx.x & 63, wave = threadIdx.x >> 6;
    int incl = c;
    for (int off = 1; off < 64; off <<= 1) {
        int nv = __shfl_up(incl, off);
        if (lane >= off) incl += nv;
    }
    __shared__ int ws[4];
    if (lane == 63) ws[wave] = incl;
    __syncthreads();
    int base = 0;
    for (int w = 0; w < 3; ++w) if (w < wave) base += ws[w];
    if (i < n) rowptr[i] = partial[blockIdx.x] + base + incl - c;
}

__global__ void fill_k(const int* __restrict__ ei, int E,
                       const int* __restrict__ rowptr, int* __restrict__ cur,
                       int* __restrict__ csr) {
    int e = blockIdx.x * 256 + threadIdx.x;
    if (e < E) {
        int d = ei[E + e];
        int pos = rowptr[d] + atomicAdd(&cur[d], 1);
        csr[pos] = ei[e];
    }
}

// ---------------- weight convert: Wb[n][k] bf16, k = [Wl row | Wr row] ------

__global__ void wtb_k(const float* __restrict__ Wl, const float* __restrict__ Wr,
                      uint* __restrict__ wb) {
    int i = blockIdx.x * 256 + threadIdx.x;   // 0..16383  (128 rows x 128 u32)
    if (i >= 128 * 128) return;
    int nrow = i >> 7;
    int k = (i & 127) * 2;
    const float* W = (k < 128) ? Wl : Wr;
    int kk = k & 127;
    uint lo = bf16r(W[nrow * 128 + kk]);
    uint hi = bf16r(W[nrow * 128 + kk + 1]);
    wb[i] = (hi << 16) | lo;
}

// ---------------- f32 -> packed bf16 pairs ----------------

__global__ void cvt_k(const float* __restrict__ in, uint* __restrict__ out, int nquad) {
    int i = blockIdx.x * 256 + threadIdx.x;
    if (i >= nquad) return;
    float4 v = ((const float4*)in)[i];
    uint2 p;
    p.x = (bf16r(v.y) << 16) | bf16r(v.x);
    p.y = (bf16r(v.w) << 16) | bf16r(v.z);
    ((uint2*)out)[i] = p;
}

// ---------------- mean aggregation: bf16 gather -> f32 accum -> bf16 out ----
// 256 thr = 16 nodes x 16 uint4-columns (16 B/lane, 256 B/row); 4-way unroll.

#define ACC8(v)                                             \
    s0 += bflo(v.x); s1 += bfhi(v.x); s2 += bflo(v.y); s3 += bfhi(v.y); \
    s4 += bflo(v.z); s5 += bfhi(v.z); s6 += bflo(v.w); s7 += bfhi(v.w);

__global__ __launch_bounds__(256) void agg_k(
    const uint4* __restrict__ xb,
    const int* __restrict__ count, const int* __restrict__ rowptr,
    const int* __restrict__ csr, uint4* __restrict__ aggb, int N) {
    int t = threadIdx.x;
    int n = blockIdx.x * 16 + (t >> 4);
    if (n >= N) return;
    int c = t & 15;
    int deg = count[n];
    int ro  = rowptr[n];
    float s0=0,s1=0,s2=0,s3=0,s4=0,s5=0,s6=0,s7=0;
    int i = 0;
    for (; i + 4 <= deg; i += 4) {
        int e0 = csr[ro + i], e1 = csr[ro + i + 1];
        int e2 = csr[ro + i + 2], e3 = csr[ro + i + 3];
        uint4 v0 = xb[(size_t)e0 * 16 + c];
        uint4 v1 = xb[(size_t)e1 * 16 + c];
        uint4 v2 = xb[(size_t)e2 * 16 + c];
        uint4 v3 = xb[(size_t)e3 * 16 + c];
        ACC8(v0); ACC8(v1); ACC8(v2); ACC8(v3);
    }
    for (; i < deg; ++i) {
        int e0 = csr[ro + i];
        uint4 v0 = xb[(size_t)e0 * 16 + c];
        ACC8(v0);
    }
    float inv = (deg > 0) ? (1.f / (float)deg) : 0.f;
    uint4 r;
    r.x = (bf16r(s1 * inv) << 16) | bf16r(s0 * inv);
    r.y = (bf16r(s3 * inv) << 16) | bf16r(s2 * inv);
    r.z = (bf16r(s5 * inv) << 16) | bf16r(s4 * inv);
    r.w = (bf16r(s7 * inv) << 16) | bf16r(s6 * inv);
    aggb[(size_t)n * 16 + c] = r;
}

// ---------------- MFMA transform ----------------
// C[m 32][n 32] per wave; K=256 (Ab0 k<128, Ab1 k>=128). B-frags (W) live in
// 64 VGPRs, A-frags straight from global (no cross-block A reuse at N=128).
// Layouts (v_mfma_f32_32x32x16_bf16): A row=lane&31, k=(lane>>5)*8+i;
// B col=lane&31, same k; C col=lane&31, row=(reg&3)+8*(reg>>2)+4*(lane>>5).

__global__ __launch_bounds__(256) void mfma_transform_k(
    const ushort* __restrict__ Ab0,   // aggb [.][128] bf16
    const ushort* __restrict__ Ab1,   // xb or hb [.][128] bf16
    const ushort* __restrict__ Wb,    // [128][256] bf16 (n-major, k contiguous)
    const float* __restrict__ bl,
    float* __restrict__ out,          // f32 out or null
    ushort* __restrict__ hb,          // bf16 out or null
    int N, int mtiles, int relu) {
    int wid   = threadIdx.x >> 6;     // wave = n-tile 0..3
    int lane  = threadIdx.x & 63;
    int col   = lane & 31;
    int khalf = lane >> 5;
    int n     = wid * 32 + col;

    bf16x8 B[16];
    const ushort* wrow = Wb + (size_t)n * 256 + khalf * 8;
    #pragma unroll
    for (int ks = 0; ks < 16; ++ks)
        B[ks] = *reinterpret_cast<const bf16x8*>(wrow + ks * 16);

    float bias = bl[n];

    for (int mt = blockIdx.x; mt < mtiles; mt += gridDim.x) {
        int row = mt * 32 + col;
        if (row >= N) row = N - 1;                 // tail clamp (loads only)
        const ushort* ar0 = Ab0 + (size_t)row * 128 + khalf * 8;
        const ushort* ar1 = Ab1 + (size_t)row * 128 + khalf * 8;
        bf16x8 A[16];
        #pragma unroll
        for (int ks = 0; ks < 8; ++ks)
            A[ks] = *reinterpret_cast<const bf16x8*>(ar0 + ks * 16);
        #pragma unroll
        for (int ks = 0; ks < 8; ++ks)
            A[8 + ks] = *reinterpret_cast<const bf16x8*>(ar1 + ks * 16);

        f32x16 acc = {};
        #pragma unroll
        for (int ks = 0; ks < 16; ++ks)
            acc = __builtin_amdgcn_mfma_f32_32x32x16_bf16(A[ks], B[ks], acc, 0, 0, 0);

        #pragma unroll
        for (int r = 0; r < 16; ++r) {
            int rr = (r & 3) + 8 * (r >> 2) + 4 * khalf;
            int gm = mt * 32 + rr;
            if (gm < N) {
                float v = acc[r] + bias;
                if (relu) v = fmaxf(v, 0.f);
                if (out) out[(size_t)gm * 128 + n] = v;
                if (hb)  hb[(size_t)gm * 128 + n] = (ushort)bf16r(v);
            }
        }
    }
}

extern "C" void kernel_launch(void* const* d_in, const int* in_sizes, int n_in,
                              void* d_out, int out_size, void* d_ws, size_t ws_size,
                              hipStream_t stream) {
    const float* x  = (const float*)d_in[0];
    const int*   ei = (const int*)d_in[1];
    const float* Wl = (const float*)d_in[2];
    const float* bl = (const float*)d_in[3];
    const float* Wr = (const float*)d_in[4];
    float* out = (float*)d_out;

    const int N = NN;
    const int E = in_sizes[1] / 2;
    const int NPAD = 50016;

    // ws layout (u32 units):
    // count[N] | cur[N] | rowptr[N] | partial[256] | csr[E] | wb[16384]
    // | xb[NPAD*64] | hb[NPAD*64] | aggb[NPAD*64]
    int* ws      = (int*)d_ws;
    int* count   = ws;
    int* cur     = ws + N;
    int* rowptr  = ws + 2 * N;
    int* partial = ws + 3 * N;
    int* csr     = ws + 3 * N + 256;
    uint* wb     = (uint*)(ws + 3 * N + 256 + E);          // offset 790256 (16B-aligned)
    uint* xb     = wb + 128 * 128;
    uint* hb     = xb + (size_t)NPAD * 64;
    uint* aggb   = hb + (size_t)NPAD * 64;

    hipMemsetAsync(count, 0, (size_t)2 * N * sizeof(int), stream);  // count + cur

    int eb = (E + 255) / 256;
    int nchunk = (N + 255) / 256;
    hist_k<<<eb, 256, 0, stream>>>(ei, E, count);
    chunk_sum_k<<<nchunk, 256, 0, stream>>>(count, N, partial);
    scan_block_k<<<1, 256, 0, stream>>>(partial, nchunk);
    rowptr_k<<<nchunk, 256, 0, stream>>>(count, partial, N, rowptr);
    fill_k<<<eb, 256, 0, stream>>>(ei, E, rowptr, cur, csr);
    wtb_k<<<64, 256, 0, stream>>>(Wl, Wr, wb);
    cvt_k<<<(N * 32 + 255) / 256, 256, 0, stream>>>(x, xb, N * 32);

    int mtiles = (N + 31) / 32;        // 1563
    int aggBlocks = (N + 15) / 16;     // 3125
    // layer 1: agg(xb)->aggb ; transform -> hb (bf16 only)
    agg_k<<<aggBlocks, 256, 0, stream>>>((const uint4*)xb, count, rowptr, csr,
                                         (uint4*)aggb, N);
    mfma_transform_k<<<mtiles, 256, 0, stream>>>((const ushort*)aggb, (const ushort*)xb,
                                                 (const ushort*)wb, bl,
                                                 (float*)nullptr, (ushort*)hb, N, mtiles, 1);
    // layer 2: agg(hb)->aggb ; transform -> out (f32)
    agg_k<<<aggBlocks, 256, 0, stream>>>((const uint4*)hb, count, rowptr, csr,
                                         (uint4*)aggb, N);
    mfma_transform_k<<<mtiles, 256, 0, stream>>>((const ushort*)aggb, (const ushort*)hb,
                                                 (const ushort*)wb, bl,
                                                 out, (ushort*)nullptr, N, mtiles, 0);
}

// Round 6
// 171.245 us; speedup vs baseline: 4.5603x; 1.1843x over previous
//
#include <hip/hip_runtime.h>

#define NN 50000
#define D 128

typedef short bf16x8 __attribute__((ext_vector_type(8)));
typedef float f32x16 __attribute__((ext_vector_type(16)));

__device__ __forceinline__ unsigned bf16r(float f) {   // RNE round to bf16
    unsigned u = __float_as_uint(f);
    return (u + 0x7FFFu + ((u >> 16) & 1u)) >> 16;
}
__device__ __forceinline__ float bflo(unsigned u) { return __uint_as_float(u << 16); }
__device__ __forceinline__ float bfhi(unsigned u) { return __uint_as_float(u & 0xFFFF0000u); }

// ---------------- zero (replaces runtime fillBuffer: was 42us in timed graph) --

__global__ void zero_k(uint4* __restrict__ p, int nq) {
    int i = blockIdx.x * 256 + threadIdx.x;
    if (i < nq) { uint4 z = {0, 0, 0, 0}; p[i] = z; }
}

// ---------------- CSR build ----------------

__global__ void hist_k(const int* __restrict__ ei, int E, int* __restrict__ count) {
    int e = blockIdx.x * 256 + threadIdx.x;
    if (e < E) atomicAdd(&count[ei[E + e]], 1);
}

__global__ void chunk_sum_k(const int* __restrict__ count, int n, int* __restrict__ partial) {
    int i = blockIdx.x * 256 + threadIdx.x;
    int v = (i < n) ? count[i] : 0;
    for (int off = 32; off; off >>= 1) v += __shfl_down(v, off);
    __shared__ int ws[4];
    int lane = threadIdx.x & 63, wave = threadIdx.x >> 6;
    if (lane == 0) ws[wave] = v;
    __syncthreads();
    if (threadIdx.x == 0) partial[blockIdx.x] = ws[0] + ws[1] + ws[2] + ws[3];
}

// parallel exclusive scan over <=256 chunk sums
__global__ void scan_block_k(int* partial, int nchunk) {
    __shared__ int sm[256];
    int t = threadIdx.x;
    int v = (t < nchunk) ? partial[t] : 0;
    sm[t] = v;
    __syncthreads();
    for (int off = 1; off < 256; off <<= 1) {
        int add = (t >= off) ? sm[t - off] : 0;
        __syncthreads();
        sm[t] += add;
        __syncthreads();
    }
    if (t < nchunk) partial[t] = sm[t] - v;   // exclusive
}

__global__ void rowptr_k(const int* __restrict__ count, const int* __restrict__ partial,
                         int n, int* __restrict__ rowptr) {
    int i = blockIdx.x * 256 + threadIdx.x;
    int c = (i < n) ? count[i] : 0;
    int lane = threadIdx.x & 63, wave = threadIdx.x >> 6;
    int incl = c;
    for (int off = 1; off < 64; off <<= 1) {
        int nv = __shfl_up(incl, off);
        if (lane >= off) incl += nv;
    }
    __shared__ int ws[4];
    if (lane == 63) ws[wave] = incl;
    __syncthreads();
    int base = 0;
    for (int w = 0; w < 3; ++w) if (w < wave) base += ws[w];
    if (i < n) rowptr[i] = partial[blockIdx.x] + base + incl - c;
}

// fill consumes count via atomicSub (rowptr_k already done with it); no cur array
__global__ void fill_k(const int* __restrict__ ei, int E,
                       const int* __restrict__ rowptr, int* __restrict__ count,
                       int* __restrict__ csr) {
    int e = blockIdx.x * 256 + threadIdx.x;
    if (e < E) {
        int d = ei[E + e];
        int slot = atomicSub(&count[d], 1) - 1;
        csr[rowptr[d] + slot] = ei[e];
    }
}

// ---------------- weight convert: Wb[n][k] bf16, k = [Wl row | Wr row] ------

__global__ void wtb_k(const float* __restrict__ Wl, const float* __restrict__ Wr,
                      uint* __restrict__ wb) {
    int i = blockIdx.x * 256 + threadIdx.x;   // 0..16383  (128 rows x 128 u32)
    if (i >= 128 * 128) return;
    int nrow = i >> 7;
    int k = (i & 127) * 2;
    const float* W = (k < 128) ? Wl : Wr;
    int kk = k & 127;
    uint lo = bf16r(W[nrow * 128 + kk]);
    uint hi = bf16r(W[nrow * 128 + kk + 1]);
    wb[i] = (hi << 16) | lo;
}

// ---------------- f32 -> packed bf16 pairs ----------------

__global__ void cvt_k(const float* __restrict__ in, uint* __restrict__ out, int nquad) {
    int i = blockIdx.x * 256 + threadIdx.x;
    if (i >= nquad) return;
    float4 v = ((const float4*)in)[i];
    uint2 p;
    p.x = (bf16r(v.y) << 16) | bf16r(v.x);
    p.y = (bf16r(v.w) << 16) | bf16r(v.z);
    ((uint2*)out)[i] = p;
}

// ---------------- fused layer: agg(32 nodes) -> LDS -> MFMA transform ----------
// Block = one 32-row m-tile.
// Phase 1: 256 thr = 16 nodes x 16 uint4-cols, 2 groups; mean-gather bf16 rows
//          (f32 accum), pack bf16 into LDS At[row][c16 ^ (row&7)] (swizzle puts
//          phase-2 column reads at the 4-cyc structural LDS floor).
// Phase 2: wave = 32-col n-tile; B(W) 64 VGPR from global, A0 from LDS,
//          A1 (self row) from global; 16x mfma_f32_32x32x16_bf16.
// C/D layout: col=lane&31, row=(reg&3)+8*(reg>>2)+4*(lane>>5)  [m74/m101]

__global__ __launch_bounds__(256) void fused_layer_k(
    const uint4* __restrict__ in4,    // bf16 rows [N][16 uint4]: gather src AND A1
    const int* __restrict__ rowptr,
    const int* __restrict__ csr,
    const ushort* __restrict__ Wb,    // [128][256] bf16 (n-major, k contiguous)
    const float* __restrict__ bl,
    float* __restrict__ out,          // f32 out or null
    ushort* __restrict__ hb,          // bf16 out or null
    int N, int E, int relu) {
    __shared__ uint4 At[32][16];

    int tid = threadIdx.x;
    int mt  = blockIdx.x;

    // ---- phase 1: aggregate ----
    int lnode = tid >> 4;
    int c16   = tid & 15;
    #pragma unroll
    for (int g = 0; g < 2; ++g) {
        int lrow = g * 16 + lnode;
        int n = mt * 32 + lrow;
        float s0=0,s1=0,s2=0,s3=0,s4=0,s5=0,s6=0,s7=0;
        float inv = 0.f;
        if (n < N) {
            int ro = rowptr[n];
            int re = (n == N - 1) ? E : rowptr[n + 1];
            int deg = re - ro;
            int i = 0;
            for (; i + 4 <= deg; i += 4) {
                int e0 = csr[ro + i],     e1 = csr[ro + i + 1];
                int e2 = csr[ro + i + 2], e3 = csr[ro + i + 3];
                uint4 v0 = in4[(size_t)e0 * 16 + c16];
                uint4 v1 = in4[(size_t)e1 * 16 + c16];
                uint4 v2 = in4[(size_t)e2 * 16 + c16];
                uint4 v3 = in4[(size_t)e3 * 16 + c16];
                s0 += bflo(v0.x)+bflo(v1.x)+bflo(v2.x)+bflo(v3.x);
                s1 += bfhi(v0.x)+bfhi(v1.x)+bfhi(v2.x)+bfhi(v3.x);
                s2 += bflo(v0.y)+bflo(v1.y)+bflo(v2.y)+bflo(v3.y);
                s3 += bfhi(v0.y)+bfhi(v1.y)+bfhi(v2.y)+bfhi(v3.y);
                s4 += bflo(v0.z)+bflo(v1.z)+bflo(v2.z)+bflo(v3.z);
                s5 += bfhi(v0.z)+bfhi(v1.z)+bfhi(v2.z)+bfhi(v3.z);
                s6 += bflo(v0.w)+bflo(v1.w)+bflo(v2.w)+bflo(v3.w);
                s7 += bfhi(v0.w)+bfhi(v1.w)+bfhi(v2.w)+bfhi(v3.w);
            }
            for (; i < deg; ++i) {
                uint4 v0 = in4[(size_t)csr[ro + i] * 16 + c16];
                s0 += bflo(v0.x); s1 += bfhi(v0.x);
                s2 += bflo(v0.y); s3 += bfhi(v0.y);
                s4 += bflo(v0.z); s5 += bfhi(v0.z);
                s6 += bflo(v0.w); s7 += bfhi(v0.w);
            }
            inv = (deg > 0) ? (1.f / (float)deg) : 0.f;
        }
        uint4 r;
        r.x = (bf16r(s1 * inv) << 16) | bf16r(s0 * inv);
        r.y = (bf16r(s3 * inv) << 16) | bf16r(s2 * inv);
        r.z = (bf16r(s5 * inv) << 16) | bf16r(s4 * inv);
        r.w = (bf16r(s7 * inv) << 16) | bf16r(s6 * inv);
        At[lrow][c16 ^ (lrow & 7)] = r;
    }
    __syncthreads();

    // ---- phase 2: MFMA ----
    int wid   = tid >> 6;
    int lane  = tid & 63;
    int col   = lane & 31;
    int khalf = lane >> 5;
    int nfeat = wid * 32 + col;

    bf16x8 B[16], A[16];
    const ushort* wrow = Wb + (size_t)nfeat * 256 + khalf * 8;
    #pragma unroll
    for (int ks = 0; ks < 16; ++ks)
        B[ks] = *reinterpret_cast<const bf16x8*>(wrow + ks * 16);

    #pragma unroll
    for (int ks = 0; ks < 8; ++ks) {
        int cc = (ks * 2 + khalf) ^ (col & 7);
        A[ks] = *reinterpret_cast<const bf16x8*>(&At[col][cc]);
    }
    int rowc = min(mt * 32 + col, N - 1);
    const ushort* ar1 = (const ushort*)in4 + (size_t)rowc * 128 + khalf * 8;
    #pragma unroll
    for (int ks = 0; ks < 8; ++ks)
        A[8 + ks] = *reinterpret_cast<const bf16x8*>(ar1 + ks * 16);

    f32x16 acc = {};
    #pragma unroll
    for (int ks = 0; ks < 16; ++ks)
        acc = __builtin_amdgcn_mfma_f32_32x32x16_bf16(A[ks], B[ks], acc, 0, 0, 0);

    float bias = bl[nfeat];
    #pragma unroll
    for (int r = 0; r < 16; ++r) {
        int rr = (r & 3) + 8 * (r >> 2) + 4 * khalf;
        int gm = mt * 32 + rr;
        if (gm < N) {
            float v = acc[r] + bias;
            if (relu) v = fmaxf(v, 0.f);
            if (out) out[(size_t)gm * 128 + nfeat] = v;
            if (hb)  hb[(size_t)gm * 128 + nfeat] = (ushort)bf16r(v);
        }
    }
}

extern "C" void kernel_launch(void* const* d_in, const int* in_sizes, int n_in,
                              void* d_out, int out_size, void* d_ws, size_t ws_size,
                              hipStream_t stream) {
    const float* x  = (const float*)d_in[0];
    const int*   ei = (const int*)d_in[1];
    const float* Wl = (const float*)d_in[2];
    const float* bl = (const float*)d_in[3];
    const float* Wr = (const float*)d_in[4];
    float* out = (float*)d_out;

    const int N = NN;
    const int E = in_sizes[1] / 2;
    const int NPAD = 50016;

    // ws layout (u32 units): count[N] | rowptr[N] | partial[256] | csr[E]
    //                        | wb[16384] | xb[NPAD*64] | hb[NPAD*64]
    int* ws      = (int*)d_ws;
    int* count   = ws;
    int* rowptr  = ws + N;
    int* partial = ws + 2 * N;
    int* csr     = ws + 2 * N + 256;
    uint* wb     = (uint*)(ws + 2 * N + 256 + E);   // u32 off 740256: 16B-aligned
    uint* xb     = wb + 128 * 128;
    uint* hb     = xb + (size_t)NPAD * 64;

    int eb = (E + 255) / 256;
    int nchunk = (N + 255) / 256;

    zero_k<<<(N / 4 + 255) / 256, 256, 0, stream>>>((uint4*)count, N / 4);  // N%4==0
    hist_k<<<eb, 256, 0, stream>>>(ei, E, count);
    chunk_sum_k<<<nchunk, 256, 0, stream>>>(count, N, partial);
    scan_block_k<<<1, 256, 0, stream>>>(partial, nchunk);
    rowptr_k<<<nchunk, 256, 0, stream>>>(count, partial, N, rowptr);
    fill_k<<<eb, 256, 0, stream>>>(ei, E, rowptr, count, csr);
    wtb_k<<<64, 256, 0, stream>>>(Wl, Wr, wb);
    cvt_k<<<(N * 32 + 255) / 256, 256, 0, stream>>>(x, xb, N * 32);

    int mtiles = (N + 31) / 32;        // 1563
    // layer 1: gather from xb, output bf16 hb only
    fused_layer_k<<<mtiles, 256, 0, stream>>>((const uint4*)xb, rowptr, csr,
                                              (const ushort*)wb, bl,
                                              (float*)nullptr, (ushort*)hb, N, E, 1);
    // layer 2: gather from hb, output f32 out
    fused_layer_k<<<mtiles, 256, 0, stream>>>((const uint4*)hb, rowptr, csr,
                                              (const ushort*)wb, bl,
                                              out, (ushort*)nullptr, N, E, 0);
}